// Round 1
// baseline (18.903 us; speedup 1.0000x reference)
//
#include <hip/hip_runtime.h>

// IntrinsicLoss: out[b] = || A_b w_b ||^2 where A_b is built from X[b,0:6].
// Memory-bound elementwise op. 2 rows per thread => perfectly aligned
// float4 loads (2 X-rows = 3 x float4, 2 W-rows = 2 x float4), float2 store.

__device__ __forceinline__ float row_loss(float x0, float x1, float x2,
                                          float x3, float x4, float x5,
                                          float w0, float w1, float w2, float w3) {
    // r_i = dot(A_row_i, w); A rows per reference:
    // row0 = [x0*x2 + x1*x3, x0 + x2, x1 + x3, 1]
    // row1 = [x0*x4 + x1*x5, x0 + x4, x1 + x5, 1]
    // row2 = [x2*x4 + x3*x5, x2 + x4, x3 + x5, 1]
    float r0 = fmaf(fmaf(x0, x2, x1 * x3), w0,
               fmaf(x0 + x2, w1, fmaf(x1 + x3, w2, w3)));
    float r1 = fmaf(fmaf(x0, x4, x1 * x5), w0,
               fmaf(x0 + x4, w1, fmaf(x1 + x5, w2, w3)));
    float r2 = fmaf(fmaf(x2, x4, x3 * x5), w0,
               fmaf(x2 + x4, w1, fmaf(x3 + x5, w2, w3)));
    return fmaf(r0, r0, fmaf(r1, r1, r2 * r2));
}

__global__ __launch_bounds__(256) void IntrinsicLoss_kernel(
    const float4* __restrict__ X4,   // X viewed as float4[]; 3 per row-pair
    const float4* __restrict__ W4,   // W viewed as float4[]; 2 per row-pair
    float2* __restrict__ out2,       // out viewed as float2[]; 1 per row-pair
    int npairs, int odd,
    const float* __restrict__ Xs,    // scalar views for odd tail
    const float* __restrict__ Ws,
    float* __restrict__ outs)
{
    int idx = blockIdx.x * blockDim.x + threadIdx.x;
    if (idx < npairs) {
        // rows 2*idx and 2*idx+1
        float4 a = X4[idx * 3 + 0];  // xA0 xA1 xA2 xA3
        float4 b = X4[idx * 3 + 1];  // xA4 xA5 xB0 xB1
        float4 c = X4[idx * 3 + 2];  // xB2 xB3 xB4 xB5
        float4 wa = W4[idx * 2 + 0];
        float4 wb = W4[idx * 2 + 1];
        float la = row_loss(a.x, a.y, a.z, a.w, b.x, b.y,
                            wa.x, wa.y, wa.z, wa.w);
        float lb = row_loss(b.z, b.w, c.x, c.y, c.z, c.w,
                            wb.x, wb.y, wb.z, wb.w);
        out2[idx] = make_float2(la, lb);
    } else if (odd && idx == npairs) {
        // tail: last (odd) row, scalar path
        int r = 2 * npairs;
        float l = row_loss(Xs[r * 6 + 0], Xs[r * 6 + 1], Xs[r * 6 + 2],
                           Xs[r * 6 + 3], Xs[r * 6 + 4], Xs[r * 6 + 5],
                           Ws[r * 4 + 0], Ws[r * 4 + 1], Ws[r * 4 + 2],
                           Ws[r * 4 + 3]);
        outs[r] = l;
    }
}

extern "C" void kernel_launch(void* const* d_in, const int* in_sizes, int n_in,
                              void* d_out, int out_size, void* d_ws, size_t ws_size,
                              hipStream_t stream) {
    const float* X = (const float*)d_in[0];   // [B, 6] fp32
    const float* W = (const float*)d_in[1];   // [B, 4] fp32
    float* out = (float*)d_out;               // [B] fp32

    int B = in_sizes[0] / 6;
    int npairs = B / 2;
    int odd = B & 1;
    int nthreads = npairs + odd;
    int grid = (nthreads + 255) / 256;

    IntrinsicLoss_kernel<<<grid, 256, 0, stream>>>(
        (const float4*)X, (const float4*)W, (float2*)out,
        npairs, odd, X, W, out);
}